// Round 8
// baseline (273.919 us; speedup 1.0000x reference)
//
#include <hip/hip_runtime.h>
#include <stdint.h>

// QNetSNN: B=16384, HIDDEN=64, T=40. Wave=row, lane=neuron.
// R8 = R4 (proven 204.5us; LDS pipe ~95% saturated) + fold-stream split:
// 6/16 waves read fold64 from LDS, 10/16 from a global f64 replica via
// NON-TEMPORAL loads (so the 32KB L1 pair set is not evicted — the variable
// R5 didn't control). Inner loops keep R4's exact 2-wide predicated shape.
//
// LDS 64 KB (f64): wsrec64 [k][n] | fold64 = Wcin[:,64:]+Wcrec [k][n]
// ws: wsin32[0,3072) | wain32[3072,3584) | pair float2 @3584 (16384 f32)
//     | foldG f64 @ f32-idx 19968 (4096 doubles, 32 KB)

__device__ __forceinline__ uint64_t rfl64(uint64_t x) {
    uint32_t lo = (uint32_t)__builtin_amdgcn_readfirstlane((int)(uint32_t)(x & 0xFFFFFFFFull));
    uint32_t hi = (uint32_t)__builtin_amdgcn_readfirstlane((int)(uint32_t)(x >> 32));
    return ((uint64_t)hi << 32) | (uint64_t)lo;
}

__global__ void snn_prep(const float* __restrict__ Wsin, const float* __restrict__ Wain,
                         const float* __restrict__ Warec, const float* __restrict__ Wcin,
                         const float* __restrict__ Wcrec, float* __restrict__ ws) {
    int tid = blockIdx.x * 256 + threadIdx.x;   // 0..15871
    if (tid < 3072) {
        int k = tid >> 6, n = tid & 63;
        ws[tid] = Wsin[n * 48 + k];
    } else if (tid < 3584) {
        int r = tid - 3072; int k = r >> 6, n = r & 63;
        ws[tid] = Wain[n * 8 + k];
    } else if (tid < 11776) {
        int r = tid - 3584; int k = r >> 7; int rem = r & 127; int n = rem >> 1;
        ws[tid] = (rem & 1) ? Wcin[n * 128 + k]    // .y = Wcin1 (cols :64)
                            : Warec[n * 64 + k];   // .x = Warec
    } else if (tid < 15872) {
        int r = tid - 11776; int k = r >> 6, n = r & 63;
        double* foldG = (double*)(ws + 19968);
        foldG[r] = (double)Wcin[n * 128 + 64 + k] + (double)Wcrec[n * 64 + k];
    }
}

__launch_bounds__(1024, 4)
__global__ void snn_main(const float* __restrict__ state, const float* __restrict__ action,
                         const float* __restrict__ Wsrec, const float* __restrict__ Wcin,
                         const float* __restrict__ Wcrec, const float* __restrict__ Wro,
                         const float* __restrict__ ws, float* __restrict__ out) {
    __shared__ double lds[8192];  // [0,4096) wsrec64 [k][n]; [4096,8192) fold64 [k][n]

    const int tid = threadIdx.x;
    for (int e = tid; e < 8192; e += 1024) {
        int half = e >> 12; int sub = e & 4095; int k = sub >> 6; int n = sub & 63;
        double val;
        if (half == 0) val = (double)Wsrec[n * 64 + k];
        else           val = (double)Wcin[n * 128 + 64 + k] + (double)Wcrec[n * 64 + k];
        lds[e] = val;
    }
    __syncthreads();

    const int lane = tid & 63;
    const int wave = tid >> 6;
    const int row  = blockIdx.x * 16 + wave;
    const bool foldLds = (wave & 15) < 6;        // 6/16 waves: fold from LDS

    double cur = 0.0;
    if (lane < 24)      cur = fmax( 50.0 * (double)state[row * 24 + lane], 0.0);
    else if (lane < 48) cur = fmax(-50.0 * (double)state[row * 24 + lane - 24], 0.0);
    else if (lane < 52) cur = fmax( 50.0 * (double)action[row * 4 + lane - 48], 0.0);
    else if (lane < 56) cur = fmax(-50.0 * (double)action[row * 4 + lane - 52], 0.0);

    // Always-on lanes: venc = 0.1*cur bit-identically each step -> exact predicate.
    double v1 = 0.0 + 0.1 * (cur - 0.0);
    bool alw = (v1 - 1.0) > 0.0;
    double curv = alw ? 0.0 : cur;
    uint64_t AM = rfl64(__ballot(alw));

    const float*  __restrict__ wsin32 = ws;
    const float*  __restrict__ wain32 = ws + 3072;
    const float2* __restrict__ pair   = (const float2*)(ws + 3584);
    const double* __restrict__ foldG  = (const double*)(ws + 19968);
    const float wro = Wro[lane];

    double Ssin = 0.0, Sain = 0.0;
    {
        uint64_t m = AM & 0x0000FFFFFFFFFFFFull;
        while (m) { int k = __builtin_ctzll(m); m &= m - 1; Ssin += (double)wsin32[(k << 6) + lane]; }
        m = AM >> 48;
        while (m) { int k = __builtin_ctzll(m); m &= m - 1; Sain += (double)wain32[(k << 6) + lane]; }
    }

    double venc = 0.0, v = 0.0, icur = 0.0, vli = 0.0, ili = 0.0, vmax = 0.0;
    uint64_t zmask = 0;  // z_c of previous step

    for (int t = 0; t < 40; ++t) {
        // ---- layer-s threshold (entering v,i only) ----
        double vd = v + 0.1 * (icur - v);
        bool zs = (vd - 1.0) > 0.0;
        double vs_new = zs ? 0.0 : vd;
        uint64_t zsm = rfl64(__ballot(zs));

        // ---- pair loop (global f32x2, L1-resident): Warec + Wcin1 ----
        double pA0 = 0.0, pA1 = 0.0, pC0 = 0.0, pC1 = 0.0;
        {
            uint64_t m = zsm;
            while (m) {
                int k = __builtin_ctzll(m); m &= m - 1;
                float2 w = pair[(k << 6) + lane];
                pA0 += (double)w.x; pC0 += (double)w.y;
                if (m) {
                    k = __builtin_ctzll(m); m &= m - 1;
                    float2 u = pair[(k << 6) + lane];
                    pA1 += (double)u.x; pC1 += (double)u.y;
                }
            }
        }

        // ---- encoder (variable lanes only) ----
        venc = venc + 0.1 * (curv - venc);
        bool esp = (venc - 1.0) > 0.0;
        venc = esp ? 0.0 : venc;
        uint64_t em = rfl64(__ballot(esp));

        // ---- layer s accumulation: zmask -> wsrec (LDS f64) ----
        double acc = (icur - 0.2 * icur) + Ssin;
        {
            uint64_t m = em & 0x0000FFFFFFFFFFFFull;
            while (m) { int k = __builtin_ctzll(m); m &= m - 1; acc += (double)wsin32[(k << 6) + lane]; }
            double a0 = 0.0, a1 = 0.0;
            m = zmask;
            while (m) {
                int k = __builtin_ctzll(m); m &= m - 1; a0 += lds[(k << 6) + lane];
                if (m) { k = __builtin_ctzll(m); m &= m - 1; a1 += lds[(k << 6) + lane]; }
            }
            acc += a0 + a1;
        }
        double icur_s = acc;

        // ---- layer a ----
        vd = vs_new + 0.1 * (icur_s - vs_new);
        bool za = (vd - 1.0) > 0.0;
        double va_new = za ? 0.0 : vd;
        uint64_t zam = rfl64(__ballot(za));

        acc = (icur_s - 0.2 * icur_s) + Sain + (pA0 + pA1);
        {
            uint64_t m = (em >> 48);
            while (m) { int k = __builtin_ctzll(m); m &= m - 1; acc += (double)wain32[(k << 6) + lane]; }
        }
        double icur_a = acc;

        // ---- layer c: zam -> fold64; 6/16 waves LDS, 10/16 global-NT ----
        vd = va_new + 0.1 * (icur_a - va_new);
        bool zc = (vd - 1.0) > 0.0;
        v = zc ? 0.0 : vd;
        zmask = rfl64(__ballot(zc));

        double f0 = 0.0, f1 = 0.0;
        if (foldLds) {
            uint64_t m = zam;
            while (m) {
                int k = __builtin_ctzll(m); m &= m - 1;
                f0 += lds[4096 + (k << 6) + lane];
                if (m) { k = __builtin_ctzll(m); m &= m - 1; f1 += lds[4096 + (k << 6) + lane]; }
            }
        } else {
            uint64_t m = zam;
            while (m) {
                int k = __builtin_ctzll(m); m &= m - 1;
                f0 += __builtin_nontemporal_load(&foldG[(k << 6) + lane]);
                if (m) { k = __builtin_ctzll(m); m &= m - 1; f1 += __builtin_nontemporal_load(&foldG[(k << 6) + lane]); }
            }
        }
        icur = (icur_a - 0.2 * icur_a) + (pC0 + pC1) + (f0 + f1);

        // ---- LI readout (feed-forward -> f32 reduce safe) ----
        float p = zc ? wro : 0.f;
        #pragma unroll
        for (int off = 32; off >= 1; off >>= 1) p += __shfl_xor(p, off, 64);
        double vnew = vli + 0.1 * (ili - vli);
        ili = (ili - 0.2 * ili) + (double)p;
        vli = vnew;
        vmax = fmax(vmax, vli);
    }

    if (lane == 0) out[row] = (float)vmax;
}

extern "C" void kernel_launch(void* const* d_in, const int* in_sizes, int n_in,
                              void* d_out, int out_size, void* d_ws, size_t ws_size,
                              hipStream_t stream) {
    const float* state  = (const float*)d_in[0];
    const float* action = (const float*)d_in[1];
    const float* Wsin   = (const float*)d_in[2];
    const float* Wsrec  = (const float*)d_in[3];
    const float* Wain   = (const float*)d_in[4];
    const float* Warec  = (const float*)d_in[5];
    const float* Wcin   = (const float*)d_in[6];
    const float* Wcrec  = (const float*)d_in[7];
    const float* Wro    = (const float*)d_in[8];
    float* out = (float*)d_out;
    float* ws  = (float*)d_ws;

    const int B = in_sizes[0] / 24;  // 16384
    snn_prep<<<62, 256, 0, stream>>>(Wsin, Wain, Warec, Wcin, Wcrec, ws);
    snn_main<<<B / 16, 1024, 0, stream>>>(state, action, Wsrec, Wcin, Wcrec, Wro, ws, out);
}